// Round 6
// baseline (460.704 us; speedup 1.0000x reference)
//
#include <hip/hip_runtime.h>
#include <hip/hip_bf16.h>
#include <stdint.h>

#define D_MODEL 1024
#define SEQ     2048
#define NBATCH  4
#define NHEAD   16
#define MROWS   (NBATCH*SEQ)   // 8192

typedef __attribute__((ext_vector_type(8))) short short8;
typedef __attribute__((ext_vector_type(4))) float floatx4;
typedef __attribute__((ext_vector_type(2))) unsigned int uint2v;

#if __has_builtin(__builtin_amdgcn_exp2f)
#define EXP2(x) __builtin_amdgcn_exp2f(x)
#else
#define EXP2(x) exp2f(x)
#endif

__device__ __forceinline__ unsigned short f2bf(float f) {
  unsigned int x;
  __builtin_memcpy(&x, &f, 4);
  x += 0x7fffu + ((x >> 16) & 1u);   // RNE (finite values)
  return (unsigned short)(x >> 16);
}

__device__ __forceinline__ unsigned int pk2(float a, float b) {
  __hip_bfloat162 h = __float22bfloat162_rn(make_float2(a, b));  // v_cvt_pk_bf16_f32
  unsigned int u;
  __builtin_memcpy(&u, &h, 4);
  return u;
}

__device__ __forceinline__ short8 pack8(floatx4 lo, floatx4 hi) {
  union { short8 s; unsigned int u[4]; } r;
  r.u[0] = pk2(lo[0], lo[1]);
  r.u[1] = pk2(lo[2], lo[3]);
  r.u[2] = pk2(hi[0], hi[1]);
  r.u[3] = pk2(hi[2], hi[3]);
  return r.s;
}

__device__ __forceinline__ void gl_lds16(const unsigned short* g, unsigned short* l) {
  __builtin_amdgcn_global_load_lds(
      (const __attribute__((address_space(1))) unsigned int*)g,
      (__attribute__((address_space(3))) unsigned int*)l, 16, 0, 0);
}

// f32 -> bf16 conversion, 8 elems/thread, memory-bound.
__global__ __launch_bounds__(256)
void cvt_f32_bf16(const float* __restrict__ src, unsigned short* __restrict__ dst, int n8) {
  const int i = blockIdx.x * 256 + threadIdx.x;
  if (i < n8) {
    const floatx4 a = *(const floatx4*)(src + (size_t)i*8);
    const floatx4 b = *(const floatx4*)(src + (size_t)i*8 + 4);
    *(short8*)(dst + (size_t)i*8) = pack8(a, b);
  }
}

// Y[M,N] = (A[M,K] @ W[N,K]^T + bias[N]) * scale.
// A: bf16 (staged via global_load_lds width=16, zero VALU).
// W: f32 (L2-resident, on-the-fly cvt_pk during staging).
// 128x128 tile, BK=32, 256 threads (4 waves), each wave a 64x64 quadrant.
template <bool OUT_F32>
__global__ __launch_bounds__(256)
void gemm_bt_bias(const unsigned short* __restrict__ A,
                  const float* __restrict__ W,
                  const float* __restrict__ bias,
                  void* __restrict__ Y_,
                  int M, int N, int K, float scale) {
  __shared__ unsigned short As[128*32];
  __shared__ unsigned short Bs[128*32];
  const int tid  = threadIdx.x;
  const int lane = tid & 63;
  const int w    = tid >> 6;
  const int rho  = lane & 15;
  const int quad = lane >> 4;
  const int ntile = N >> 7;
  const int bx = blockIdx.x % ntile;
  const int by = blockIdx.x / ntile;
  const int tm = by << 7, tn = bx << 7;
  const int wrow = (w >> 1) << 6;
  const int wcol = (w & 1) << 6;

  // granules: tile = 128 rows x 4 chunks of 16B; granule g -> row g>>2, chunk g&3,
  // LDS byte offset g*16 (contiguous in lane order -> valid global_load_lds dst).
  const int g0 = tid, g1 = tid + 256;
  const unsigned short* ga0 = A + (size_t)(tm + (g0 >> 2))*K + (g0 & 3)*8;
  const unsigned short* ga1 = A + (size_t)(tm + (g1 >> 2))*K + (g1 & 3)*8;
  unsigned short* la0 = &As[(w*64)*8];          // wave-uniform base, lane*16B implicit
  unsigned short* la1 = &As[(256 + w*64)*8];

  const int wr0 = g0 >> 2, wc0 = g0 & 3;
  const int wr1 = g1 >> 2, wc1 = g1 & 3;
  const float* gw0 = W + (size_t)(tn + wr0)*K + wc0*8;
  const float* gw1 = W + (size_t)(tn + wr1)*K + wc1*8;

  floatx4 acc[4][4] = {};

  for (int kk = 0; kk < K; kk += 32) {
    // W f32 loads + cvt into VGPRs (latency overlaps the barrier wait)
    const short8 b0 = pack8(*(const floatx4*)(gw0 + kk), *(const floatx4*)(gw0 + kk + 4));
    const short8 b1 = pack8(*(const floatx4*)(gw1 + kk), *(const floatx4*)(gw1 + kk + 4));
    __syncthreads();   // prior iteration's fragment reads complete
    gl_lds16(ga0 + kk, la0);
    gl_lds16(ga1 + kk, la1);
    *(short8*)&Bs[wr0*32 + wc0*8] = b0;
    *(short8*)&Bs[wr1*32 + wc1*8] = b1;
    __syncthreads();   // drains vmcnt (gl_lds) + lgkm (ds_write) for all waves

    short8 af[4], bfrag[4];
#pragma unroll
    for (int i = 0; i < 4; i++) {
      af[i]    = *(const short8*)&As[(wrow + i*16 + rho)*32 + quad*8];
      bfrag[i] = *(const short8*)&Bs[(wcol + i*16 + rho)*32 + quad*8];
    }
#pragma unroll
    for (int i = 0; i < 4; i++)
#pragma unroll
      for (int j = 0; j < 4; j++)
        acc[i][j] = __builtin_amdgcn_mfma_f32_16x16x32_bf16(af[i], bfrag[j], acc[i][j], 0, 0, 0);
  }

  float bj[4];
#pragma unroll
  for (int j = 0; j < 4; j++) bj[j] = bias[tn + wcol + j*16 + rho];
#pragma unroll
  for (int i = 0; i < 4; i++) {
    const int grow = tm + wrow + i*16 + (quad << 2);
#pragma unroll
    for (int j = 0; j < 4; j++) {
      const int gcol = tn + wcol + j*16 + rho;
#pragma unroll
      for (int r = 0; r < 4; r++) {
        const float val = (acc[i][j][r] + bj[j]) * scale;
        if (OUT_F32)
          ((float*)Y_)[(size_t)(grow + r)*N + gcol] = val;
        else
          ((unsigned short*)Y_)[(size_t)(grow + r)*N + gcol] = f2bf(val);
      }
    }
  }
}

// Fused flash attention v3 (unchanged from round 5, minus dead code).
__global__ __launch_bounds__(256, 3)
void attn_fused(const unsigned short* __restrict__ Qp,
                const unsigned short* __restrict__ Kp,
                const unsigned short* __restrict__ Vp,
                unsigned short* __restrict__ AO) {
  __shared__ unsigned short Ks[2][64*64];   // rotated granules, 8 KB each
  __shared__ unsigned short Vt[2][64*72];   // [dk][kappa], stride 72 shorts
  __shared__ unsigned short Pl[4][32*72];   // per-wave P [row][kappa]

  const int tid  = threadIdx.x;
  const int w    = tid >> 6;
  const int lane = tid & 63;
  const int rho  = lane & 15;
  const int quad = lane >> 4;

  const int qt = blockIdx.x & 15;           // 16 q-tiles of 128
  const int bh = blockIdx.x >> 4;
  const int b  = bh >> 4;
  const int h  = bh & 15;
  const size_t base = (size_t)b*SEQ*D_MODEL + h*64;
  const unsigned short* Qb = Qp + base;
  const unsigned short* Kb = Kp + base;
  const unsigned short* Vb = Vp + base;

  const int q0 = qt*128 + w*32;

  short8 aq[2][2];
#pragma unroll
  for (int u = 0; u < 2; u++) {
    const unsigned short* qr = Qb + (size_t)(q0 + u*16 + rho)*D_MODEL + quad*8;
    aq[u][0] = *(const short8*)qr;
    aq[u][1] = *(const short8*)(qr + 32);
  }

  float lsum[2][4] = {};
  floatx4 oacc[2][4] = {};

  const int vkey = tid & 63;
  const int vh   = tid >> 6;                               // wave-uniform
  const int vkap = ((vkey & 15) << 2) | (vkey >> 4);       // kappa(key)

  const int s0i = w*64 + lane;
  const int k0key = s0i >> 3, k0g = ((s0i & 7) - k0key) & 7;
  const int s1i = 256 + w*64 + lane;
  const int k1key = s1i >> 3, k1g = ((s1i & 7) - k1key) & 7;

  const int kp0 = (quad + rho) & 7;
  const int kp1 = (kp0 + 4) & 7;

  gl_lds16(Kb + (size_t)k0key*D_MODEL + k0g*8, &Ks[0][(w*64)*8]);
  gl_lds16(Kb + (size_t)k1key*D_MODEL + k1g*8, &Ks[0][(256 + w*64)*8]);

  for (int kb = 0; kb < SEQ; kb += 64) {
    const int bi = (kb >> 6) & 1;

    {
      const unsigned short* vr = Vb + (size_t)(kb + vkey)*D_MODEL + vh*16;
      const short8 v0 = *(const short8*)vr;
      const short8 v1 = *(const short8*)(vr + 8);
      unsigned short* dst = &Vt[bi][vh*16*72 + vkap];
#pragma unroll
      for (int e = 0; e < 8; e++) dst[e*72] = (unsigned short)v0[e];
#pragma unroll
      for (int e = 0; e < 8; e++) dst[(8 + e)*72] = (unsigned short)v1[e];
    }
    __syncthreads();   // drains K prefetch (vmcnt) + makes Vt[bi] visible

    if (kb + 64 < SEQ) {
      unsigned short* kn = &Ks[bi ^ 1][0];
      gl_lds16(Kb + (size_t)(kb + 64 + k0key)*D_MODEL + k0g*8, kn + (w*64)*8);
      gl_lds16(Kb + (size_t)(kb + 64 + k1key)*D_MODEL + k1g*8, kn + (256 + w*64)*8);
    }

    const unsigned short* ks = &Ks[bi][0];
    floatx4 s[2][4];
#pragma unroll
    for (int gk = 0; gk < 4; gk++) {
      const int key = gk*16 + rho;
      const short8 kf0 = *(const short8*)(ks + (key*8 + kp0)*8);
      const short8 kf1 = *(const short8*)(ks + (key*8 + kp1)*8);
#pragma unroll
      for (int u = 0; u < 2; u++) {
        floatx4 t = {0.f, 0.f, 0.f, 0.f};
        t = __builtin_amdgcn_mfma_f32_16x16x32_bf16(aq[u][0], kf0, t, 0, 0, 0);
        t = __builtin_amdgcn_mfma_f32_16x16x32_bf16(aq[u][1], kf1, t, 0, 0, 0);
        s[u][gk] = t;
      }
    }

#pragma unroll
    for (int u = 0; u < 2; u++)
#pragma unroll
      for (int r = 0; r < 4; r++) {
        const float e0 = EXP2(s[u][0][r]);
        const float e1 = EXP2(s[u][1][r]);
        const float e2 = EXP2(s[u][2][r]);
        const float e3 = EXP2(s[u][3][r]);
        lsum[u][r] += (e0 + e1) + (e2 + e3);
        const unsigned int lo = pk2(e0, e1);
        const unsigned int hi = pk2(e2, e3);
        const int row = u*16 + (quad << 2) + r;
        *(uint2v*)&Pl[w][row*72 + rho*4] = (uint2v){lo, hi};
      }
    // no barrier: P is per-wave; in-wave LDS ordering via lgkmcnt

    short8 bv[4][2];
#pragma unroll
    for (int c = 0; c < 4; c++) {
      bv[c][0] = *(const short8*)&Vt[bi][(c*16 + rho)*72 + quad*8];
      bv[c][1] = *(const short8*)&Vt[bi][(c*16 + rho)*72 + 32 + quad*8];
    }
#pragma unroll
    for (int u = 0; u < 2; u++) {
      const short8 ap0 = *(const short8*)&Pl[w][(u*16 + rho)*72 + quad*8];
      const short8 ap1 = *(const short8*)&Pl[w][(u*16 + rho)*72 + 32 + quad*8];
#pragma unroll
      for (int c = 0; c < 4; c++) {
        oacc[u][c] = __builtin_amdgcn_mfma_f32_16x16x32_bf16(ap0, bv[c][0], oacc[u][c], 0, 0, 0);
        oacc[u][c] = __builtin_amdgcn_mfma_f32_16x16x32_bf16(ap1, bv[c][1], oacc[u][c], 0, 0, 0);
      }
    }
  }

#pragma unroll
  for (int d = 1; d < 16; d <<= 1)
#pragma unroll
    for (int u = 0; u < 2; u++)
#pragma unroll
      for (int r = 0; r < 4; r++) lsum[u][r] += __shfl_xor(lsum[u][r], d);

#pragma unroll
  for (int u = 0; u < 2; u++) {
    float inv[4];
#pragma unroll
    for (int r = 0; r < 4; r++) inv[r] = 1.0f / lsum[u][r];
#pragma unroll
    for (int c = 0; c < 4; c++)
#pragma unroll
      for (int r = 0; r < 4; r++)
        AO[base + (size_t)(q0 + u*16 + (quad << 2) + r)*D_MODEL + c*16 + rho] =
            f2bf(oacc[u][c][r] * inv[r]);
  }
}

extern "C" void kernel_launch(void* const* d_in, const int* in_sizes, int n_in,
                              void* d_out, int out_size, void* d_ws, size_t ws_size,
                              hipStream_t stream) {
  const float* q  = (const float*)d_in[0];
  const float* k  = (const float*)d_in[1];
  const float* v  = (const float*)d_in[2];
  const float* wq = (const float*)d_in[3];
  const float* bq = (const float*)d_in[4];
  const float* wk = (const float*)d_in[5];
  const float* bk = (const float*)d_in[6];
  const float* wv = (const float*)d_in[7];
  const float* bv = (const float*)d_in[8];
  const float* wo = (const float*)d_in[9];
  const float* bo = (const float*)d_in[10];
  float* out = (float*)d_out;

  // 4 slots x 16MB (bf16 8192x1024). S3 is serially reused: cvt scratch -> AO.
  const size_t SLOT = (size_t)MROWS * D_MODEL;
  unsigned short* S0 = (unsigned short*)d_ws;      // Qp
  unsigned short* S1 = S0 + SLOT;                  // Kp
  unsigned short* S2 = S1 + SLOT;                  // Vp
  unsigned short* S3 = S2 + SLOT;                  // xb (cvt) then AO

  const float qscale = 0.125f * 1.4426950408889634f;  // 1/sqrt(dk) * log2(e)

  const dim3 blk(256);
  const dim3 ggrid((D_MODEL/128) * (MROWS/128));   // 512
  const int n8 = (int)(SLOT / 8);                  // 1M cvt work-items
  const dim3 cgrid((n8 + 255) / 256);

  cvt_f32_bf16<<<cgrid, blk, 0, stream>>>(q, S3, n8);
  gemm_bt_bias<false><<<ggrid, blk, 0, stream>>>(S3, wq, bq, S0, MROWS, D_MODEL, D_MODEL, qscale);
  cvt_f32_bf16<<<cgrid, blk, 0, stream>>>(k, S3, n8);
  gemm_bt_bias<false><<<ggrid, blk, 0, stream>>>(S3, wk, bk, S1, MROWS, D_MODEL, D_MODEL, 1.0f);
  cvt_f32_bf16<<<cgrid, blk, 0, stream>>>(v, S3, n8);
  gemm_bt_bias<false><<<ggrid, blk, 0, stream>>>(S3, wv, bv, S2, MROWS, D_MODEL, D_MODEL, 1.0f);
  attn_fused<<<dim3(NBATCH*NHEAD*(SEQ/128)), blk, 0, stream>>>(S0, S1, S2, S3);
  gemm_bt_bias<true><<<ggrid, blk, 0, stream>>>(S3, wo, bo, out, MROWS, D_MODEL, D_MODEL, 1.0f);
}